// Round 7
// baseline (171.385 us; speedup 1.0000x reference)
//
#include <hip/hip_runtime.h>

#define NG 8000
#define V1 2562
#define V2 10242
#define V3 40962
#define E1 7680
#define E2 30720
#define E3 122880
#define NPRED (V1 + V2 + V3)   /* 53766 */
#define ND1   (3 * NG)         /* 24000 */
#define NMIN  (ND1 + NPRED)    /* 77766 */
#define ABATCH 16
#define MAXCHUNK 512

struct PassTab {
    int NA[6], NB[6], h[6], xb[6], chunk[6], ooff[6], base[7];
};

__device__ __forceinline__ float min3f(float a, float b, float c) {
    float r;
    asm("v_min3_f32 %0, %1, %2, %3" : "=v"(r) : "v"(a), "v"(b), "v"(c));
    return r;
}

__device__ __forceinline__ double block_reduce_add(double v, double* sm) {
    int lane = threadIdx.x & 63;
    int wid  = threadIdx.x >> 6;
    for (int off = 32; off > 0; off >>= 1) v += __shfl_down(v, off, 64);
    if (lane == 0) sm[wid] = v;
    __syncthreads();
    double r = 0.0;
    if (wid == 0) {
        int nw = blockDim.x >> 6;
        r = (lane < nw) ? sm[lane] : 0.0;
        for (int off = 32; off > 0; off >>= 1) r += __shfl_down(r, off, 64);
    }
    return r;  /* valid on thread 0 */
}

__global__ void k_init(unsigned int* __restrict__ mins, double* __restrict__ acc) {
    int i = blockIdx.x * blockDim.x + threadIdx.x;
    if (i < 8) acc[i] = 0.0;
    int stride = gridDim.x * blockDim.x;
    for (int k = i; k < NMIN; k += stride) mins[k] = 0x7f800000u; /* +inf */
}

/* All six chamfer passes, ONE launch, atomicMin outputs.
   Block -> (pass, xblk, yblk); B-chunk staged in LDS (norms on the fly);
   thread owns 16 A points. Inner loop: 4-b ping-pong — LDS reads for the
   next 2 b's issue between the two FMA half-blocks, so the lgkm wait
   overlaps ~224cy of FMAs instead of stalling (r6 lesson: exposed LDS
   latency at low occupancy cost ~45%). min3 via inline asm = 3.5
   VALU/pair guaranteed. Tracks m = min_j (Bn - 2*A.B); result
   max(An + m, 0) >= 0 so float-as-uint atomicMin ordering is valid. */
__launch_bounds__(256)
__global__ void k_pair_all(const float* __restrict__ gt,
                           const float* __restrict__ q1,
                           const float* __restrict__ q2,
                           const float* __restrict__ q3,
                           unsigned int* __restrict__ mins, PassTab T) {
    __shared__ float4 sb[MAXCHUNK];
    int bid = blockIdx.x, tid = threadIdx.x;

    int p = 0;
    while (p < 5 && bid >= T.base[p + 1]) ++p;  /* wave-uniform */
    int rel  = bid - T.base[p];
    int xb   = T.xb[p];
    int xblk = rel % xb, yblk = rel / xb;
    int NA = T.NA[p], NB = T.NB[p], h = T.h[p], chunk = T.chunk[p];
    int pi = (p < 3) ? p : p - 3;
    const float* pr = (pi == 0) ? q1 : ((pi == 1) ? q2 : q3);
    const float* A  = (p < 3) ? gt : pr;
    const float* B  = (p < 3) ? pr : gt;

    int j0 = yblk * chunk;
    int cnt = min(NB - j0, chunk);
    for (int i = tid; i < cnt; i += 256) {
        int j = 3 * (j0 + i);
        float x = B[j], y = B[j + 1], z = B[j + 2];
        sb[i] = make_float4(x, y, z, fmaf(x, x, fmaf(y, y, z * z)));
    }
    __syncthreads();

    int t = xblk * 256 + tid;
    if (t >= h) return;

    float nx[ABATCH], ny_[ABATCH], nz[ABATCH], aw[ABATCH], m[ABATCH];
#pragma unroll
    for (int q = 0; q < ABATCH; ++q) {
        int tq = t + q * h; if (tq > NA - 1) tq = NA - 1;
        int j = 3 * tq;
        float x = A[j], y = A[j + 1], z = A[j + 2];
        nx[q] = -2.f * x; ny_[q] = -2.f * y; nz[q] = -2.f * z;
        aw[q] = fmaf(x, x, fmaf(y, y, z * z));
        m[q] = __builtin_inff();
    }

#define DOT(q, bb) fmaf(nz[q], bb.z, fmaf(ny_[q], bb.y, fmaf(nx[q], bb.x, bb.w)))
    int k = 0;
    float4 c0, c1;
    if (cnt >= 2) { c0 = sb[0]; c1 = sb[1]; }
    for (; k + 6 <= cnt; k += 4) {
        float4 e0 = sb[k + 2], e1 = sb[k + 3];   /* prefetch pair 2 */
#pragma unroll
        for (int q = 0; q < ABATCH; ++q) {
            float d0 = DOT(q, c0), d1 = DOT(q, c1);
            m[q] = min3f(m[q], d0, d1);
        }
        c0 = sb[k + 4]; c1 = sb[k + 5];          /* prefetch next iter */
#pragma unroll
        for (int q = 0; q < ABATCH; ++q) {
            float d0 = DOT(q, e0), d1 = DOT(q, e1);
            m[q] = min3f(m[q], d0, d1);
        }
    }
    for (; k < cnt; ++k) {
        float4 b = sb[k];
#pragma unroll
        for (int q = 0; q < ABATCH; ++q) m[q] = fminf(m[q], DOT(q, b));
    }
#undef DOT

    unsigned int* out = mins + T.ooff[p];
#pragma unroll
    for (int q = 0; q < ABATCH; ++q) {
        int tq = t + q * h;
        if (tq < NA) atomicMin(out + tq, __float_as_uint(fmaxf(aw[q] + m[q], 0.f)));
    }
}

/* chamfer means + edge + laplace, one kernel (r4-proven structure). */
#define R0 NMIN
#define R1 (E1 + E2 + E3)
#define R2 NPRED
__global__ void k_post(const unsigned int* __restrict__ mins,
                       const float* __restrict__ p1, const float* __restrict__ p2,
                       const float* __restrict__ p3,
                       const int* __restrict__ e1, const int* __restrict__ e2,
                       const int* __restrict__ e3,
                       const float* __restrict__ f1, const float* __restrict__ f2,
                       const float* __restrict__ f3,
                       const int* __restrict__ l1, const int* __restrict__ l2,
                       const int* __restrict__ l3,
                       double* __restrict__ acc) {
    __shared__ double sm[8];
    double s0 = 0.0, s1 = 0.0, s2 = 0.0;
    int stride = gridDim.x * blockDim.x;
    int gid = blockIdx.x * blockDim.x + threadIdx.x;
    for (int i = gid; i < R0 + R1 + R2; i += stride) {
        if (i < R0) {
            double w;
            if (i < ND1) w = 1.0 / NG;
            else {
                int t = i - ND1;
                w = (t < V1) ? (1.0 / V1) : ((t < V1 + V2) ? (1.0 / V2) : (1.0 / V3));
            }
            s0 += (double)__uint_as_float(mins[i]) * w;
        } else if (i < R0 + R1) {
            int q = i - R0;
            const float* p; const int* e; int k; double w;
            if (q < E1)            { p = p1; e = e1; k = q;            w = 1.0 / E1; }
            else if (q < E1 + E2)  { p = p2; e = e2; k = q - E1;       w = 1.0 / E2; }
            else                   { p = p3; e = e3; k = q - E1 - E2;  w = 1.0 / E3; }
            int u = e[2 * k], v = e[2 * k + 1];
            float dx = p[3 * u]     - p[3 * v];
            float dy = p[3 * u + 1] - p[3 * v + 1];
            float dz = p[3 * u + 2] - p[3 * v + 2];
            s1 += w * (double)(dx * dx + dy * dy + dz * dz);
        } else {
            int q = i - R0 - R1;
            const float* f; const float* p; const int* l; int k; double w;
            if (q < V1)            { f = f1; p = p1; l = l1; k = q;            w = 0.2 / V1; }
            else if (q < V1 + V2)  { f = f2; p = p2; l = l2; k = q - V1;       w = 1.0 / V2; }
            else                   { f = f3; p = p3; l = l3; k = q - V1 - V2;  w = 1.0 / V3; }
            const int* row = l + 10 * k;
            float sfx = 0.f, sfy = 0.f, sfz = 0.f, spx = 0.f, spy = 0.f, spz = 0.f;
#pragma unroll
            for (int r = 0; r < 8; ++r) {
                int n = row[r];
                if (n >= 0) {
                    sfx += f[3 * n]; sfy += f[3 * n + 1]; sfz += f[3 * n + 2];
                    spx += p[3 * n]; spy += p[3 * n + 1]; spz += p[3 * n + 2];
                }
            }
            float inv = 1.0f / (float)row[9];
            float dx = (f[3 * k]     - p[3 * k])     - (sfx - spx) * inv;
            float dy = (f[3 * k + 1] - p[3 * k + 1]) - (sfy - spy) * inv;
            float dz = (f[3 * k + 2] - p[3 * k + 2]) - (sfz - spz) * inv;
            s2 += w * (double)(dx * dx + dy * dy + dz * dz);
        }
    }
    double r0 = block_reduce_add(s0, sm); __syncthreads();
    double r1 = block_reduce_add(s1, sm); __syncthreads();
    double r2 = block_reduce_add(s2, sm);
    if (threadIdx.x == 0) {
        atomicAdd(acc + 0, r0);
        atomicAdd(acc + 1, r1);
        atomicAdd(acc + 2, r2);
    }
}

__global__ void k_final(const double* __restrict__ acc, float* __restrict__ out) {
    if (threadIdx.x == 0 && blockIdx.x == 0) {
        double ch = acc[0], ed = acc[1], lp = acc[2];
        out[0] = (float)(100.0 * ch + 0.1 * ed + 0.3 * lp);
        out[1] = (float)ch;
        out[2] = (float)ed;
        out[3] = (float)lp;
    }
}

static void build_tab(PassTab& T) {
    const int NAs[6]  = { NG, NG, NG, V1, V2, V3 };
    const int NBs[6]  = { V1, V2, V3, NG, NG, NG };
    const int ooff[6] = { 0, NG, 2 * NG, ND1, ND1 + V1, ND1 + V1 + V2 };
    const double totalPairs = 2.0 * ((double)NG * NPRED);
    const int TARGET_BLOCKS = 2048;           /* r6 lesson: 1024 starved occupancy */
    int base = 0;
    for (int p = 0; p < 6; ++p) {
        int NA = NAs[p], NB = NBs[p];
        int h  = (NA + ABATCH - 1) / ABATCH;
        int xb = (h + 255) / 256;
        double share = ((double)NA * NB) / totalPairs;
        int ny = (int)(share * TARGET_BLOCKS / xb + 0.5);
        int nyMin = (NB + MAXCHUNK - 1) / MAXCHUNK;   /* chunk <= 512 */
        int nyMax = NB / 96;                          /* chunk >= 96  */
        if (nyMax < nyMin) nyMax = nyMin;
        if (ny < nyMin) ny = nyMin;
        if (ny > nyMax) ny = nyMax;
        int chunk = (NB + ny - 1) / ny;
        ny = (NB + chunk - 1) / chunk;                /* all chunks nonempty */
        T.NA[p] = NA; T.NB[p] = NB; T.h[p] = h; T.xb[p] = xb;
        T.chunk[p] = chunk; T.ooff[p] = ooff[p]; T.base[p] = base;
        base += xb * ny;
    }
    T.base[6] = base;
}

extern "C" void kernel_launch(void* const* d_in, const int* in_sizes, int n_in,
                              void* d_out, int out_size, void* d_ws, size_t ws_size,
                              hipStream_t stream) {
    const float *pp[3], *pf[3], *gt;
    const int *ed[3], *li[3];
    if (in_sizes[1] == 3 * V1) {
        /* setup_inputs() dict order: (pts,feats,edges,lap)*3, gt */
        pp[0] = (const float*)d_in[0];  pf[0] = (const float*)d_in[1];
        ed[0] = (const int*)d_in[2];    li[0] = (const int*)d_in[3];
        pp[1] = (const float*)d_in[4];  pf[1] = (const float*)d_in[5];
        ed[1] = (const int*)d_in[6];    li[1] = (const int*)d_in[7];
        pp[2] = (const float*)d_in[8];  pf[2] = (const float*)d_in[9];
        ed[2] = (const int*)d_in[10];   li[2] = (const int*)d_in[11];
        gt = (const float*)d_in[12];
    } else {
        /* reference signature order */
        pp[0] = (const float*)d_in[0];  pp[1] = (const float*)d_in[1];  pp[2] = (const float*)d_in[2];
        pf[0] = (const float*)d_in[3];  pf[1] = (const float*)d_in[4];  pf[2] = (const float*)d_in[5];
        gt    = (const float*)d_in[6];
        ed[0] = (const int*)d_in[7];    ed[1] = (const int*)d_in[8];    ed[2] = (const int*)d_in[9];
        li[0] = (const int*)d_in[10];   li[1] = (const int*)d_in[11];   li[2] = (const int*)d_in[12];
    }

    PassTab T;
    build_tab(T);

    char* ws = (char*)d_ws;
    double*       acc  = (double*)ws;              /* 8 doubles      */
    unsigned int* mins = (unsigned int*)(ws + 64); /* NMIN uints     */

    k_init<<<160, 256, 0, stream>>>(mins, acc);
    k_pair_all<<<T.base[6], 256, 0, stream>>>(gt, pp[0], pp[1], pp[2], mins, T);
    k_post<<<256, 256, 0, stream>>>(mins, pp[0], pp[1], pp[2],
                                    ed[0], ed[1], ed[2],
                                    pf[0], pf[1], pf[2],
                                    li[0], li[1], li[2], acc);
    k_final<<<1, 64, 0, stream>>>(acc, (float*)d_out);
}

// Round 8
// 162.129 us; speedup vs baseline: 1.0571x; 1.0571x over previous
//
#include <hip/hip_runtime.h>

#define NG 8000
#define V1 2562
#define V2 10242
#define V3 40962
#define E1 7680
#define E2 30720
#define E3 122880
#define NPRED (V1 + V2 + V3)   /* 53766 */
#define NPK   (NG + NPRED)     /* 61766 */
#define ND1   (3 * NG)         /* 24000 */
#define NMIN  (ND1 + NPRED)    /* 77766 */
#define CHUNK 512              /* B points per block (LDS-staged)  */
#define AAW   128              /* A points per wave (8 tiles of 16) */
#define ABLK  512              /* A points per block (4 waves)      */

typedef __attribute__((ext_vector_type(8))) short bf16x8;
typedef __attribute__((ext_vector_type(4))) float f32x4;

struct PassTab { int NA[6], NB[6], Aoff[6], Boff[6], ooff[6], xb[6], base[7]; };

__device__ __forceinline__ float min3f(float a, float b, float c) {
    float r;
    asm("v_min3_f32 %0, %1, %2, %3" : "=v"(r) : "v"(a), "v"(b), "v"(c));
    return r;
}

__device__ __forceinline__ unsigned short f2bf(float f) {
    unsigned int u = __float_as_uint(f);
    return (unsigned short)((u + 0x7fffu + ((u >> 16) & 1u)) >> 16);  /* RNE */
}
__device__ __forceinline__ float bf2f(unsigned short b) {
    return __uint_as_float(((unsigned int)b) << 16);
}
__device__ __forceinline__ unsigned int pk(unsigned short lo, unsigned short hi) {
    return (unsigned int)lo | ((unsigned int)hi << 16);
}

__device__ __forceinline__ double block_reduce_add(double v, double* sm) {
    int lane = threadIdx.x & 63;
    int wid  = threadIdx.x >> 6;
    for (int off = 32; off > 0; off >>= 1) v += __shfl_down(v, off, 64);
    if (lane == 0) sm[wid] = v;
    __syncthreads();
    double r = 0.0;
    if (wid == 0) {
        int nw = blockDim.x >> 6;
        r = (lane < nw) ? sm[lane] : 0.0;
        for (int off = 32; off > 0; off >>= 1) r += __shfl_down(r, off, 64);
    }
    return r;  /* valid on thread 0 */
}

/* Per point (packed order: gt, p1, p2, p3):
   split x = hi + lo (bf16 RNE), norm bn = x2+y2+z2 (fp32) split bn_hi/bn_lo.
   K-slot layout (16x16x32 bf16 MFMA; lane k-slice = (lane>>4)*8 + i):
     B g0 (k0-7):  [hx,hy,hz, lx,ly,lz, bnh,bnl]
     B g1 (k8-15): [hx,hy,hz, 0,0,0,0,0]
     A g0 (k0-7):  [-2ahx,-2ahy,-2ahz, -2ahx,-2ahy,-2ahz, 1,1]
     A g1 (k8-15): [-2alx,-2aly,-2alz, 0,0,0,0,0]
     g2,g3: zeros both sides.
   => S[b][a] = bn - 2(ahi.bhi + ahi.blo + alo.bhi)   (err ~1e-4)
   Also inits mins to +inf and acc to 0. */
__global__ void k_prep(const float* __restrict__ gt,
                       const float* __restrict__ q1, const float* __restrict__ q2,
                       const float* __restrict__ q3,
                       uint4* __restrict__ Arec, uint4* __restrict__ Brec,
                       float* __restrict__ an, unsigned int* __restrict__ mins,
                       double* __restrict__ acc) {
    int stride = gridDim.x * blockDim.x;
    for (int i = blockIdx.x * blockDim.x + threadIdx.x; i < NMIN; i += stride) {
        if (i < 8) acc[i] = 0.0;
        mins[i] = 0x7f800000u;  /* +inf */
        if (i < NPK) {
            const float* src; int k;
            if (i < NG) { src = gt; k = i; }
            else {
                int t = i - NG;
                if (t < V1)            { src = q1; k = t; }
                else if (t < V1 + V2)  { src = q2; k = t - V1; }
                else                   { src = q3; k = t - V1 - V2; }
            }
            float x = src[3 * k], y = src[3 * k + 1], z = src[3 * k + 2];
            unsigned short hx = f2bf(x), hy = f2bf(y), hz = f2bf(z);
            float hxf = bf2f(hx), hyf = bf2f(hy), hzf = bf2f(hz);
            unsigned short lx = f2bf(x - hxf), ly = f2bf(y - hyf), lz = f2bf(z - hzf);
            float bn = fmaf(x, x, fmaf(y, y, z * z));
            unsigned short bnh = f2bf(bn);
            unsigned short bnl = f2bf(bn - bf2f(bnh));
            unsigned short nhx = f2bf(-2.f * hxf), nhy = f2bf(-2.f * hyf), nhz = f2bf(-2.f * hzf);
            unsigned short nlx = f2bf(-2.f * bf2f(lx)), nly = f2bf(-2.f * bf2f(ly)), nlz = f2bf(-2.f * bf2f(lz));
            size_t p = (size_t)i;
            Arec[p * 4 + 0] = make_uint4(pk(nhx, nhy), pk(nhz, nhx), pk(nhy, nhz), pk(0x3F80, 0x3F80));
            Arec[p * 4 + 1] = make_uint4(pk(nlx, nly), pk(nlz, 0), 0u, 0u);
            Arec[p * 4 + 2] = make_uint4(0u, 0u, 0u, 0u);
            Arec[p * 4 + 3] = make_uint4(0u, 0u, 0u, 0u);
            Brec[p * 2 + 0] = make_uint4(pk(hx, hy), pk(hz, lx), pk(ly, lz), pk(bnh, bnl));
            Brec[p * 2 + 1] = make_uint4(pk(hx, hy), pk(hz, 0), 0u, 0u);
            an[i] = bn;
        }
    }
}

/* All six chamfer passes, one launch, MFMA inner loop.
   Block = 4 waves; wave owns 128 A-points (8 tiles); block stages a
   512-point B-chunk (2x uint4 records/point) into LDS. Per 16-B step:
   1 ds_read_b128 (B-frag verbatim, g>=2 lanes AND-masked to 0) +
   8 MFMA + 16 v_min3. D layout: col=lane&15 (A-point), rows=4 B-points
   per lane; cross-lane min via shfl_xor 16/32 at the end. fp32 an added
   after the min (translation invariance); pad B records carry bn=+inf
   so they never win. Result >= 0 => float-as-uint atomicMin valid. */
__launch_bounds__(256)
__global__ void k_pair_mfma(const uint4* __restrict__ Arec,
                            const uint4* __restrict__ Brec,
                            const float* __restrict__ an,
                            unsigned int* __restrict__ mins, PassTab T) {
    __shared__ uint4 sb[2 * CHUNK];
    int bid = blockIdx.x, tid = threadIdx.x;

    int p = 0;
    while (p < 5 && bid >= T.base[p + 1]) ++p;
    int rel  = bid - T.base[p];
    int xb   = T.xb[p];
    int xblk = rel % xb, yblk = rel / xb;
    int NA = T.NA[p], NB = T.NB[p];
    int Aoff = T.Aoff[p], Boff = T.Boff[p], ooff = T.ooff[p];

    int j0  = yblk * CHUNK;
    int cnt = min(NB - j0, CHUNK);

    for (int i = tid; i < 2 * CHUNK; i += 256) {
        int pt = i >> 1, gg = i & 1;
        uint4 v;
        if (pt < cnt) v = Brec[(size_t)(Boff + j0 + pt) * 2 + gg];
        else          v = gg ? make_uint4(0u, 0u, 0u, 0u)
                             : make_uint4(0u, 0u, 0u, 0x00007F80u); /* bn=+inf pad */
        sb[i] = v;
    }
    __syncthreads();

    int l = tid & 63, w = tid >> 6;
    int g = l >> 4, c = l & 15;
    int Abase = xblk * ABLK + w * AAW;

    union U { uint4 u; bf16x8 b; };

    bf16x8 af[8];
    float  m[8];
#pragma unroll
    for (int tt = 0; tt < 8; ++tt) {
        int apt = Abase + tt * 16 + c;
        int ap  = min(apt, NA - 1);
        U u; u.u = Arec[(size_t)(Aoff + ap) * 4 + g];
        af[tt] = u.b;
        m[tt]  = __builtin_inff();
    }

    unsigned int msk = (g < 2) ? 0xFFFFFFFFu : 0u;
    const uint4* bbase = sb + (c * 2 + (g & 1));
    f32x4 zero = {0.f, 0.f, 0.f, 0.f};

    for (int jb = 0; jb < cnt; jb += 16) {
        uint4 r = bbase[jb * 2];
        r.x &= msk; r.y &= msk; r.z &= msk; r.w &= msk;
        U u; u.u = r;
        bf16x8 bfr = u.b;
#pragma unroll
        for (int tt = 0; tt < 8; ++tt) {
            f32x4 a = __builtin_amdgcn_mfma_f32_16x16x32_bf16(bfr, af[tt], zero, 0, 0, 0);
            float t0 = min3f(a[0], a[1], a[2]);
            m[tt] = min3f(m[tt], t0, a[3]);
        }
    }

#pragma unroll
    for (int tt = 0; tt < 8; ++tt) {
        float mm = m[tt];
        mm = fminf(mm, __shfl_xor(mm, 16, 64));
        mm = fminf(mm, __shfl_xor(mm, 32, 64));
        int apt = Abase + tt * 16 + c;
        if (g == 0 && apt < NA) {
            float d = fmaxf(an[Aoff + apt] + mm, 0.f);
            atomicMin(mins + ooff + apt, __float_as_uint(d));
        }
    }
}

/* chamfer means + edge + laplace, one kernel (r4-proven structure). */
#define R0 NMIN
#define R1 (E1 + E2 + E3)
#define R2 NPRED
__global__ void k_post(const unsigned int* __restrict__ mins,
                       const float* __restrict__ p1, const float* __restrict__ p2,
                       const float* __restrict__ p3,
                       const int* __restrict__ e1, const int* __restrict__ e2,
                       const int* __restrict__ e3,
                       const float* __restrict__ f1, const float* __restrict__ f2,
                       const float* __restrict__ f3,
                       const int* __restrict__ l1, const int* __restrict__ l2,
                       const int* __restrict__ l3,
                       double* __restrict__ acc) {
    __shared__ double sm[8];
    double s0 = 0.0, s1 = 0.0, s2 = 0.0;
    int stride = gridDim.x * blockDim.x;
    int gid = blockIdx.x * blockDim.x + threadIdx.x;
    for (int i = gid; i < R0 + R1 + R2; i += stride) {
        if (i < R0) {
            double w;
            if (i < ND1) w = 1.0 / NG;
            else {
                int t = i - ND1;
                w = (t < V1) ? (1.0 / V1) : ((t < V1 + V2) ? (1.0 / V2) : (1.0 / V3));
            }
            s0 += (double)__uint_as_float(mins[i]) * w;
        } else if (i < R0 + R1) {
            int q = i - R0;
            const float* p; const int* e; int k; double w;
            if (q < E1)            { p = p1; e = e1; k = q;            w = 1.0 / E1; }
            else if (q < E1 + E2)  { p = p2; e = e2; k = q - E1;       w = 1.0 / E2; }
            else                   { p = p3; e = e3; k = q - E1 - E2;  w = 1.0 / E3; }
            int u = e[2 * k], v = e[2 * k + 1];
            float dx = p[3 * u]     - p[3 * v];
            float dy = p[3 * u + 1] - p[3 * v + 1];
            float dz = p[3 * u + 2] - p[3 * v + 2];
            s1 += w * (double)(dx * dx + dy * dy + dz * dz);
        } else {
            int q = i - R0 - R1;
            const float* f; const float* p; const int* l; int k; double w;
            if (q < V1)            { f = f1; p = p1; l = l1; k = q;            w = 0.2 / V1; }
            else if (q < V1 + V2)  { f = f2; p = p2; l = l2; k = q - V1;       w = 1.0 / V2; }
            else                   { f = f3; p = p3; l = l3; k = q - V1 - V2;  w = 1.0 / V3; }
            const int* row = l + 10 * k;
            float sfx = 0.f, sfy = 0.f, sfz = 0.f, spx = 0.f, spy = 0.f, spz = 0.f;
#pragma unroll
            for (int r = 0; r < 8; ++r) {
                int n = row[r];
                if (n >= 0) {
                    sfx += f[3 * n]; sfy += f[3 * n + 1]; sfz += f[3 * n + 2];
                    spx += p[3 * n]; spy += p[3 * n + 1]; spz += p[3 * n + 2];
                }
            }
            float inv = 1.0f / (float)row[9];
            float dx = (f[3 * k]     - p[3 * k])     - (sfx - spx) * inv;
            float dy = (f[3 * k + 1] - p[3 * k + 1]) - (sfy - spy) * inv;
            float dz = (f[3 * k + 2] - p[3 * k + 2]) - (sfz - spz) * inv;
            s2 += w * (double)(dx * dx + dy * dy + dz * dz);
        }
    }
    double r0 = block_reduce_add(s0, sm); __syncthreads();
    double r1 = block_reduce_add(s1, sm); __syncthreads();
    double r2 = block_reduce_add(s2, sm);
    if (threadIdx.x == 0) {
        atomicAdd(acc + 0, r0);
        atomicAdd(acc + 1, r1);
        atomicAdd(acc + 2, r2);
    }
}

__global__ void k_final(const double* __restrict__ acc, float* __restrict__ out) {
    if (threadIdx.x == 0 && blockIdx.x == 0) {
        double ch = acc[0], ed = acc[1], lp = acc[2];
        out[0] = (float)(100.0 * ch + 0.1 * ed + 0.3 * lp);
        out[1] = (float)ch;
        out[2] = (float)ed;
        out[3] = (float)lp;
    }
}

static void build_tab(PassTab& T) {
    const int NAs[6]  = { NG, NG, NG, V1, V2, V3 };
    const int NBs[6]  = { V1, V2, V3, NG, NG, NG };
    const int AoP[6]  = { 0, 0, 0, NG, NG + V1, NG + V1 + V2 };
    const int BoP[6]  = { NG, NG + V1, NG + V1 + V2, 0, 0, 0 };
    const int ooP[6]  = { 0, NG, 2 * NG, ND1, ND1 + V1, ND1 + V1 + V2 };
    int base = 0;
    for (int p = 0; p < 6; ++p) {
        int xb = (NAs[p] + ABLK - 1) / ABLK;
        int ny = (NBs[p] + CHUNK - 1) / CHUNK;
        T.NA[p] = NAs[p]; T.NB[p] = NBs[p];
        T.Aoff[p] = AoP[p]; T.Boff[p] = BoP[p]; T.ooff[p] = ooP[p];
        T.xb[p] = xb; T.base[p] = base;
        base += xb * ny;
    }
    T.base[6] = base;
}

extern "C" void kernel_launch(void* const* d_in, const int* in_sizes, int n_in,
                              void* d_out, int out_size, void* d_ws, size_t ws_size,
                              hipStream_t stream) {
    const float *pp[3], *pf[3], *gt;
    const int *ed[3], *li[3];
    if (in_sizes[1] == 3 * V1) {
        /* setup_inputs() dict order: (pts,feats,edges,lap)*3, gt */
        pp[0] = (const float*)d_in[0];  pf[0] = (const float*)d_in[1];
        ed[0] = (const int*)d_in[2];    li[0] = (const int*)d_in[3];
        pp[1] = (const float*)d_in[4];  pf[1] = (const float*)d_in[5];
        ed[1] = (const int*)d_in[6];    li[1] = (const int*)d_in[7];
        pp[2] = (const float*)d_in[8];  pf[2] = (const float*)d_in[9];
        ed[2] = (const int*)d_in[10];   li[2] = (const int*)d_in[11];
        gt = (const float*)d_in[12];
    } else {
        /* reference signature order */
        pp[0] = (const float*)d_in[0];  pp[1] = (const float*)d_in[1];  pp[2] = (const float*)d_in[2];
        pf[0] = (const float*)d_in[3];  pf[1] = (const float*)d_in[4];  pf[2] = (const float*)d_in[5];
        gt    = (const float*)d_in[6];
        ed[0] = (const int*)d_in[7];    ed[1] = (const int*)d_in[8];    ed[2] = (const int*)d_in[9];
        li[0] = (const int*)d_in[10];   li[1] = (const int*)d_in[11];   li[2] = (const int*)d_in[12];
    }

    PassTab T;
    build_tab(T);

    char* ws = (char*)d_ws;
    double*       acc  = (double*)ws;                         /* 64 B            */
    unsigned int* mins = (unsigned int*)(ws + 1024);          /* NMIN u32 ~311KB */
    float*        an   = (float*)(ws + 400 * 1024);           /* NPK f32 ~247KB  */
    uint4*        Arec = (uint4*)(ws + 1024 * 1024);          /* NPK*64B ~3.95MB */
    uint4*        Brec = (uint4*)(ws + 6 * 1024 * 1024);      /* NPK*32B ~1.98MB */

    k_prep<<<256, 256, 0, stream>>>(gt, pp[0], pp[1], pp[2], Arec, Brec, an, mins, acc);
    k_pair_mfma<<<T.base[6], 256, 0, stream>>>(Arec, Brec, an, mins, T);
    k_post<<<256, 256, 0, stream>>>(mins, pp[0], pp[1], pp[2],
                                    ed[0], ed[1], ed[2],
                                    pf[0], pf[1], pf[2],
                                    li[0], li[1], li[2], acc);
    k_final<<<1, 64, 0, stream>>>(acc, (float*)d_out);
}

// Round 9
// 143.547 us; speedup vs baseline: 1.1939x; 1.1295x over previous
//
#include <hip/hip_runtime.h>

#define NG 8000
#define V1 2562
#define V2 10242
#define V3 40962
#define E1 7680
#define E2 30720
#define E3 122880
#define NPRED (V1 + V2 + V3)   /* 53766 */
#define NPK   (NG + NPRED)     /* 61766 */
#define ND1   (3 * NG)         /* 24000 */
#define NMIN  (ND1 + NPRED)    /* 77766 */
#define CHUNK 512              /* B points per block (LDS-staged)    */
#define AAW   128              /* A points per wave (4 tiles of 32)  */
#define ABLK  512              /* A points per block (4 waves)       */

typedef __attribute__((ext_vector_type(8)))  short bf16x8;
typedef __attribute__((ext_vector_type(16))) float f32x16;

struct PassTab { int NA[6], NB[6], Aoff[6], Boff[6], ooff[6], xb[6], base[7]; };

__device__ __forceinline__ unsigned short f2bf(float f) {
    unsigned int u = __float_as_uint(f);
    return (unsigned short)((u + 0x7fffu + ((u >> 16) & 1u)) >> 16);  /* RNE */
}
__device__ __forceinline__ float bf2f(unsigned short b) {
    return __uint_as_float(((unsigned int)b) << 16);
}
__device__ __forceinline__ unsigned int pk(unsigned short lo, unsigned short hi) {
    return (unsigned int)lo | ((unsigned int)hi << 16);
}

__device__ __forceinline__ double block_reduce_add(double v, double* sm) {
    int lane = threadIdx.x & 63;
    int wid  = threadIdx.x >> 6;
    for (int off = 32; off > 0; off >>= 1) v += __shfl_down(v, off, 64);
    if (lane == 0) sm[wid] = v;
    __syncthreads();
    double r = 0.0;
    if (wid == 0) {
        int nw = blockDim.x >> 6;
        r = (lane < nw) ? sm[lane] : 0.0;
        for (int off = 32; off > 0; off >>= 1) r += __shfl_down(r, off, 64);
    }
    return r;  /* valid on thread 0 */
}

/* Per point (packed order: gt, p1, p2, p3): bf16 hi/lo split + norm split.
   K-slot layout for 32x32x16 bf16 MFMA (lane k-slice = (lane>>5)*8 + i):
     B g0 (k0-7):  [hx,hy,hz, lx,ly,lz, bnh,bnl]
     B g1 (k8-15): [hx,hy,hz, 0,0,0,0,0]
     A g0 (k0-7):  [-2ahx,-2ahy,-2ahz, -2ahx,-2ahy,-2ahz, 1,1]
     A g1 (k8-15): [-2alx,-2aly,-2alz, 0,0,0,0,0]
   => S[b][a] = bn - 2(ahi.bhi + ahi.blo + alo.bhi)  (err ~1e-4)
   Also inits mins to +inf and acc to 0. */
__global__ void k_prep(const float* __restrict__ gt,
                       const float* __restrict__ q1, const float* __restrict__ q2,
                       const float* __restrict__ q3,
                       uint4* __restrict__ Arec, uint4* __restrict__ Brec,
                       float* __restrict__ an, unsigned int* __restrict__ mins,
                       double* __restrict__ acc) {
    int stride = gridDim.x * blockDim.x;
    for (int i = blockIdx.x * blockDim.x + threadIdx.x; i < NMIN; i += stride) {
        if (i < 8) acc[i] = 0.0;
        mins[i] = 0x7f800000u;  /* +inf */
        if (i < NPK) {
            const float* src; int k;
            if (i < NG) { src = gt; k = i; }
            else {
                int t = i - NG;
                if (t < V1)            { src = q1; k = t; }
                else if (t < V1 + V2)  { src = q2; k = t - V1; }
                else                   { src = q3; k = t - V1 - V2; }
            }
            float x = src[3 * k], y = src[3 * k + 1], z = src[3 * k + 2];
            unsigned short hx = f2bf(x), hy = f2bf(y), hz = f2bf(z);
            float hxf = bf2f(hx), hyf = bf2f(hy), hzf = bf2f(hz);
            unsigned short lx = f2bf(x - hxf), ly = f2bf(y - hyf), lz = f2bf(z - hzf);
            float bn = fmaf(x, x, fmaf(y, y, z * z));
            unsigned short bnh = f2bf(bn);
            unsigned short bnl = f2bf(bn - bf2f(bnh));
            unsigned short nhx = f2bf(-2.f * hxf), nhy = f2bf(-2.f * hyf), nhz = f2bf(-2.f * hzf);
            unsigned short nlx = f2bf(-2.f * bf2f(lx)), nly = f2bf(-2.f * bf2f(ly)), nlz = f2bf(-2.f * bf2f(lz));
            size_t p = (size_t)i;
            Arec[p * 2 + 0] = make_uint4(pk(nhx, nhy), pk(nhz, nhx), pk(nhy, nhz), pk(0x3F80, 0x3F80));
            Arec[p * 2 + 1] = make_uint4(pk(nlx, nly), pk(nlz, 0), 0u, 0u);
            Brec[p * 2 + 0] = make_uint4(pk(hx, hy), pk(hz, lx), pk(ly, lz), pk(bnh, bnl));
            Brec[p * 2 + 1] = make_uint4(pk(hx, hy), pk(hz, 0), 0u, 0u);
            an[i] = bn;
        }
    }
}

/* All six chamfer passes, one launch, 32x32x16 MFMA inner loop.
   Block = 4 waves; wave owns 128 A-points (4 tiles of 32); block stages
   a 512-point B-chunk (2 uint4/point) in LDS. Per 32-B step per wave:
   1 ds_read_b128 (per-lane B-record half, verbatim frag) + 4 MFMA +
   32 fmin-fold (v_min3). D: col=lane&31 = A-point; the 16 regs + the
   lane>>5 halves cover all 32 B-rows under min (permutation-robust),
   so one shfl_xor(32) finishes the row reduce. fp32 an added after the
   min (translation invariance); pad B records carry bn=+inf. Result
   >= 0 so float-as-uint atomicMin ordering is valid. */
__launch_bounds__(256)
__global__ void k_pair_mfma(const uint4* __restrict__ Arec,
                            const uint4* __restrict__ Brec,
                            const float* __restrict__ an,
                            unsigned int* __restrict__ mins, PassTab T) {
    __shared__ uint4 sb[2 * CHUNK];
    int bid = blockIdx.x, tid = threadIdx.x;

    int p = 0;
    while (p < 5 && bid >= T.base[p + 1]) ++p;
    int rel  = bid - T.base[p];
    int xb   = T.xb[p];
    int xblk = rel % xb, yblk = rel / xb;
    int NA = T.NA[p], NB = T.NB[p];
    int Aoff = T.Aoff[p], Boff = T.Boff[p], ooff = T.ooff[p];

    int j0  = yblk * CHUNK;
    int cnt = min(NB - j0, CHUNK);

    for (int i = tid; i < 2 * CHUNK; i += 256) {
        int pt = i >> 1, gg = i & 1;
        uint4 v;
        if (pt < cnt) v = Brec[(size_t)(Boff + j0 + pt) * 2 + gg];
        else          v = gg ? make_uint4(0u, 0u, 0u, 0u)
                             : make_uint4(0u, 0u, 0u, 0x00007F80u); /* bn=+inf pad */
        sb[i] = v;
    }
    __syncthreads();

    int l = tid & 63, w = tid >> 6;
    int half = l >> 5, c = l & 31;
    int Abase = xblk * ABLK + w * AAW;

    union U { uint4 u; bf16x8 b; };

    bf16x8 af[4];
    float  m[4];
#pragma unroll
    for (int tt = 0; tt < 4; ++tt) {
        int apt = Abase + tt * 32 + c;
        int ap  = min(apt, NA - 1);
        U u; u.u = Arec[(size_t)(Aoff + ap) * 2 + half];
        af[tt] = u.b;
        m[tt]  = __builtin_inff();
    }

    f32x16 zero = {0.f};

    for (int jb = 0; jb < cnt; jb += 32) {
        U u; u.u = sb[(jb + c) * 2 + half];
        bf16x8 bfr = u.b;
#pragma unroll
        for (int tt = 0; tt < 4; ++tt) {
            f32x16 d = __builtin_amdgcn_mfma_f32_32x32x16_bf16(bfr, af[tt], zero, 0, 0, 0);
            float mm = m[tt];
            mm = fminf(fminf(mm, d[0]),  d[1]);
            mm = fminf(fminf(mm, d[2]),  d[3]);
            mm = fminf(fminf(mm, d[4]),  d[5]);
            mm = fminf(fminf(mm, d[6]),  d[7]);
            mm = fminf(fminf(mm, d[8]),  d[9]);
            mm = fminf(fminf(mm, d[10]), d[11]);
            mm = fminf(fminf(mm, d[12]), d[13]);
            mm = fminf(fminf(mm, d[14]), d[15]);
            m[tt] = mm;
        }
    }

#pragma unroll
    for (int tt = 0; tt < 4; ++tt) {
        float mm = fminf(m[tt], __shfl_xor(m[tt], 32, 64));
        int apt = Abase + tt * 32 + c;
        if (half == 0 && apt < NA) {
            float d = fmaxf(an[Aoff + apt] + mm, 0.f);
            atomicMin(mins + ooff + apt, __float_as_uint(d));
        }
    }
}

/* chamfer means + edge + laplace, one kernel (r4-proven structure). */
#define R0 NMIN
#define R1 (E1 + E2 + E3)
#define R2 NPRED
__global__ void k_post(const unsigned int* __restrict__ mins,
                       const float* __restrict__ p1, const float* __restrict__ p2,
                       const float* __restrict__ p3,
                       const int* __restrict__ e1, const int* __restrict__ e2,
                       const int* __restrict__ e3,
                       const float* __restrict__ f1, const float* __restrict__ f2,
                       const float* __restrict__ f3,
                       const int* __restrict__ l1, const int* __restrict__ l2,
                       const int* __restrict__ l3,
                       double* __restrict__ acc) {
    __shared__ double sm[8];
    double s0 = 0.0, s1 = 0.0, s2 = 0.0;
    int stride = gridDim.x * blockDim.x;
    int gid = blockIdx.x * blockDim.x + threadIdx.x;
    for (int i = gid; i < R0 + R1 + R2; i += stride) {
        if (i < R0) {
            double w;
            if (i < ND1) w = 1.0 / NG;
            else {
                int t = i - ND1;
                w = (t < V1) ? (1.0 / V1) : ((t < V1 + V2) ? (1.0 / V2) : (1.0 / V3));
            }
            s0 += (double)__uint_as_float(mins[i]) * w;
        } else if (i < R0 + R1) {
            int q = i - R0;
            const float* p; const int* e; int k; double w;
            if (q < E1)            { p = p1; e = e1; k = q;            w = 1.0 / E1; }
            else if (q < E1 + E2)  { p = p2; e = e2; k = q - E1;       w = 1.0 / E2; }
            else                   { p = p3; e = e3; k = q - E1 - E2;  w = 1.0 / E3; }
            int u = e[2 * k], v = e[2 * k + 1];
            float dx = p[3 * u]     - p[3 * v];
            float dy = p[3 * u + 1] - p[3 * v + 1];
            float dz = p[3 * u + 2] - p[3 * v + 2];
            s1 += w * (double)(dx * dx + dy * dy + dz * dz);
        } else {
            int q = i - R0 - R1;
            const float* f; const float* p; const int* l; int k; double w;
            if (q < V1)            { f = f1; p = p1; l = l1; k = q;            w = 0.2 / V1; }
            else if (q < V1 + V2)  { f = f2; p = p2; l = l2; k = q - V1;       w = 1.0 / V2; }
            else                   { f = f3; p = p3; l = l3; k = q - V1 - V2;  w = 1.0 / V3; }
            const int* row = l + 10 * k;
            float sfx = 0.f, sfy = 0.f, sfz = 0.f, spx = 0.f, spy = 0.f, spz = 0.f;
#pragma unroll
            for (int r = 0; r < 8; ++r) {
                int n = row[r];
                if (n >= 0) {
                    sfx += f[3 * n]; sfy += f[3 * n + 1]; sfz += f[3 * n + 2];
                    spx += p[3 * n]; spy += p[3 * n + 1]; spz += p[3 * n + 2];
                }
            }
            float inv = 1.0f / (float)row[9];
            float dx = (f[3 * k]     - p[3 * k])     - (sfx - spx) * inv;
            float dy = (f[3 * k + 1] - p[3 * k + 1]) - (sfy - spy) * inv;
            float dz = (f[3 * k + 2] - p[3 * k + 2]) - (sfz - spz) * inv;
            s2 += w * (double)(dx * dx + dy * dy + dz * dz);
        }
    }
    double r0 = block_reduce_add(s0, sm); __syncthreads();
    double r1 = block_reduce_add(s1, sm); __syncthreads();
    double r2 = block_reduce_add(s2, sm);
    if (threadIdx.x == 0) {
        atomicAdd(acc + 0, r0);
        atomicAdd(acc + 1, r1);
        atomicAdd(acc + 2, r2);
    }
}

__global__ void k_final(const double* __restrict__ acc, float* __restrict__ out) {
    if (threadIdx.x == 0 && blockIdx.x == 0) {
        double ch = acc[0], ed = acc[1], lp = acc[2];
        out[0] = (float)(100.0 * ch + 0.1 * ed + 0.3 * lp);
        out[1] = (float)ch;
        out[2] = (float)ed;
        out[3] = (float)lp;
    }
}

static void build_tab(PassTab& T) {
    const int NAs[6]  = { NG, NG, NG, V1, V2, V3 };
    const int NBs[6]  = { V1, V2, V3, NG, NG, NG };
    const int AoP[6]  = { 0, 0, 0, NG, NG + V1, NG + V1 + V2 };
    const int BoP[6]  = { NG, NG + V1, NG + V1 + V2, 0, 0, 0 };
    const int ooP[6]  = { 0, NG, 2 * NG, ND1, ND1 + V1, ND1 + V1 + V2 };
    int base = 0;
    for (int p = 0; p < 6; ++p) {
        int xb = (NAs[p] + ABLK - 1) / ABLK;
        int ny = (NBs[p] + CHUNK - 1) / CHUNK;
        T.NA[p] = NAs[p]; T.NB[p] = NBs[p];
        T.Aoff[p] = AoP[p]; T.Boff[p] = BoP[p]; T.ooff[p] = ooP[p];
        T.xb[p] = xb; T.base[p] = base;
        base += xb * ny;
    }
    T.base[6] = base;
}

extern "C" void kernel_launch(void* const* d_in, const int* in_sizes, int n_in,
                              void* d_out, int out_size, void* d_ws, size_t ws_size,
                              hipStream_t stream) {
    const float *pp[3], *pf[3], *gt;
    const int *ed[3], *li[3];
    if (in_sizes[1] == 3 * V1) {
        /* setup_inputs() dict order: (pts,feats,edges,lap)*3, gt */
        pp[0] = (const float*)d_in[0];  pf[0] = (const float*)d_in[1];
        ed[0] = (const int*)d_in[2];    li[0] = (const int*)d_in[3];
        pp[1] = (const float*)d_in[4];  pf[1] = (const float*)d_in[5];
        ed[1] = (const int*)d_in[6];    li[1] = (const int*)d_in[7];
        pp[2] = (const float*)d_in[8];  pf[2] = (const float*)d_in[9];
        ed[2] = (const int*)d_in[10];   li[2] = (const int*)d_in[11];
        gt = (const float*)d_in[12];
    } else {
        /* reference signature order */
        pp[0] = (const float*)d_in[0];  pp[1] = (const float*)d_in[1];  pp[2] = (const float*)d_in[2];
        pf[0] = (const float*)d_in[3];  pf[1] = (const float*)d_in[4];  pf[2] = (const float*)d_in[5];
        gt    = (const float*)d_in[6];
        ed[0] = (const int*)d_in[7];    ed[1] = (const int*)d_in[8];    ed[2] = (const int*)d_in[9];
        li[0] = (const int*)d_in[10];   li[1] = (const int*)d_in[11];   li[2] = (const int*)d_in[12];
    }

    PassTab T;
    build_tab(T);

    char* ws = (char*)d_ws;
    double*       acc  = (double*)ws;                         /* 64 B            */
    unsigned int* mins = (unsigned int*)(ws + 1024);          /* NMIN u32 ~311KB */
    float*        an   = (float*)(ws + 400 * 1024);           /* NPK f32 ~247KB  */
    uint4*        Arec = (uint4*)(ws + 1024 * 1024);          /* NPK*32B ~1.98MB */
    uint4*        Brec = (uint4*)(ws + 4 * 1024 * 1024);      /* NPK*32B ~1.98MB */

    k_prep<<<256, 256, 0, stream>>>(gt, pp[0], pp[1], pp[2], Arec, Brec, an, mins, acc);
    k_pair_mfma<<<T.base[6], 256, 0, stream>>>(Arec, Brec, an, mins, T);
    k_post<<<256, 256, 0, stream>>>(mins, pp[0], pp[1], pp[2],
                                    ed[0], ed[1], ed[2],
                                    pf[0], pf[1], pf[2],
                                    li[0], li[1], li[2], acc);
    k_final<<<1, 64, 0, stream>>>(acc, (float*)d_out);
}